// Round 8
// baseline (2215.316 us; speedup 1.0000x reference)
//
#include <hip/hip_runtime.h>

// GraphEncoder: 3x (GCNConv -> [ReLU -> LayerNorm]) on N=100000 nodes, E=1.6M edges.
// Round 8: gather restructured node-per-wave -> edge-streaming into LDS fp32
// accumulators (ds_add_f32). Avg degree is only 16, so the old per-node wave had
// ~1 loop iter and was bound by its dependent-load chain + 24-op shuffle reduce.
// eidx packs (src*128 | dst&127): row byte offset + LDS-local dst in one int.

constexpr float LN_EPS = 1e-5f;
constexpr int BUCKETS = 256;
constexpr int CHUNK = 4096;
constexpr int GW = 128;        // gather window: nodes per block
constexpr int GSTRIDE = 65;    // LDS row stride (floats): spreads banks

// ---- bf16 helpers (RNE) ----
__device__ inline unsigned bf1(float x) {
    unsigned u = __float_as_uint(x);
    return (u + 0x7FFFu + ((u >> 16) & 1u)) >> 16;
}
__device__ inline unsigned bfpack(float lo, float hi) { return bf1(lo) | (bf1(hi) << 16); }
__device__ inline float bflo(unsigned r) { return __uint_as_float(r << 16); }
__device__ inline float bfhi(unsigned r) { return __uint_as_float(r & 0xFFFF0000u); }

// ---------------- hist: per-block LDS histogram of dst buckets -> partial[block][bin] ----------------
__global__ __launch_bounds__(256) void hist_kernel(const int* __restrict__ dst, int E, int bpb,
                                                   int* __restrict__ partial) {
    __shared__ int h[BUCKETS];
    const int t = threadIdx.x;
    h[t] = 0;
    __syncthreads();
    int i = blockIdx.x * blockDim.x + t;
    const int stride = gridDim.x * blockDim.x;
    for (; i < E; i += stride) atomicAdd(&h[dst[i] / bpb], 1);
    __syncthreads();
    partial[blockIdx.x * BUCKETS + t] = h[t];
}

// ---------------- scan256: column-sum partials, exclusive scan -> ebase, gcur ----------------
__global__ __launch_bounds__(256) void scan256_kernel(const int* __restrict__ partial, int nblk,
                                                      int* __restrict__ ebase, int* __restrict__ gcur) {
    __shared__ int wsum[4];
    const int t = threadIdx.x, lane = t & 63, w = t >> 6;
    int s0 = 0, s1 = 0, s2 = 0, s3 = 0;
    int i = 0;
    for (; i + 4 <= nblk; i += 4) {
        s0 += partial[(i + 0) * BUCKETS + t];
        s1 += partial[(i + 1) * BUCKETS + t];
        s2 += partial[(i + 2) * BUCKETS + t];
        s3 += partial[(i + 3) * BUCKETS + t];
    }
    for (; i < nblk; ++i) s0 += partial[i * BUCKETS + t];
    int v = s0 + s1 + s2 + s3;
    int inc = v;
#pragma unroll
    for (int off = 1; off < 64; off <<= 1) {
        int u = __shfl_up(inc, off, 64);
        if (lane >= off) inc += u;
    }
    if (lane == 63) wsum[w] = inc;
    __syncthreads();
    int woff = 0;
#pragma unroll
    for (int j = 0; j < 4; ++j)
        if (j < w) woff += wsum[j];
    int ex = woff + inc - v;
    ebase[t] = ex;
    gcur[t] = ex;
}

// ---------------- bin (pass 1): chunk -> LDS-grouped -> coalesced bursts to bucket streams ----------------
__global__ __launch_bounds__(512) void bin_kernel(const int* __restrict__ src,
                                                  const int* __restrict__ dst, int E, int bpb,
                                                  int* __restrict__ gcur,
                                                  uint2* __restrict__ binned) {
    __shared__ uint2 stag[CHUNK];
    __shared__ int cnt[BUCKETS], lstart[BUCKETS], loff[BUCKETS], gbase[BUCKETS];
    __shared__ int wsum[4];
    const int t = threadIdx.x;
    const int cb = blockIdx.x * CHUNK;
    const int csize = min(CHUNK, E - cb);

    if (t < BUCKETS) cnt[t] = 0;
    __syncthreads();

    int sr[8], dr[8];
#pragma unroll
    for (int j = 0; j < 8; ++j) {
        int i = t + j * 512;
        if (i < csize) {
            sr[j] = src[cb + i];
            dr[j] = dst[cb + i];
            atomicAdd(&cnt[dr[j] / bpb], 1);
        }
    }
    __syncthreads();

    if (t < BUCKETS) {
        const int lane = t & 63, w = t >> 6;
        int v = cnt[t];
        int inc = v;
#pragma unroll
        for (int off = 1; off < 64; off <<= 1) {
            int u = __shfl_up(inc, off, 64);
            if (lane >= off) inc += u;
        }
        if (lane == 63) wsum[w] = inc;
        __syncthreads();
        int woff = 0;
#pragma unroll
        for (int j = 0; j < 4; ++j)
            if (j < w) woff += wsum[j];
        int ex = woff + inc - v;
        lstart[t] = ex;
        loff[t] = ex;
    } else {
        __syncthreads();
    }
    __syncthreads();

#pragma unroll
    for (int j = 0; j < 8; ++j) {
        int i = t + j * 512;
        if (i < csize) {
            int b = dr[j] / bpb;
            int pos = atomicAdd(&loff[b], 1);
            stag[pos] = make_uint2((unsigned)sr[j], (unsigned)dr[j]);
        }
    }
    __syncthreads();

    if (t < BUCKETS && cnt[t] > 0) gbase[t] = atomicAdd(&gcur[t], cnt[t]);
    __syncthreads();

    for (int s = t; s < csize; s += 512) {
        uint2 p = stag[s];
        int b = (int)p.y / bpb;
        binned[gbase[b] + (s - lstart[b])] = p;
    }
}

// ---------------- build (pass 2): per-bucket deg/dinv/starts + L2-local fine scatter ----------------
// eidx entry = (src*128) | (dst & 127): row BYTE offset into T + LDS-local dst row.
__global__ __launch_bounds__(256) void build_kernel(const uint2* __restrict__ binned,
                                                    const int* __restrict__ ebase, int E, int bpb, int n,
                                                    int* __restrict__ starts,
                                                    float* __restrict__ dinv,
                                                    int* __restrict__ eidx) {
    __shared__ int degL[512];
    __shared__ int posL[512];
    __shared__ int wsum[4];
    const int t = threadIdx.x, lane = t & 63, w = t >> 6;
    const int b = blockIdx.x;
    const int nb0 = b * bpb;
    const int nloc = min(bpb, n - nb0);
    if (nloc <= 0) return;
    const int gs = ebase[b];
    const int ge = (b == BUCKETS - 1) ? E : ebase[b + 1];

    degL[t] = 0;
    degL[t + 256] = 0;
    __syncthreads();

    for (int k = gs + t; k < ge; k += 256) {
        uint2 p = binned[k];
        atomicAdd(&degL[(int)p.y - nb0], 1);
    }
    __syncthreads();

    int v0 = degL[2 * t], v1 = degL[2 * t + 1];
    int s2 = v0 + v1;
    int inc = s2;
#pragma unroll
    for (int off = 1; off < 64; off <<= 1) {
        int u = __shfl_up(inc, off, 64);
        if (lane >= off) inc += u;
    }
    if (lane == 63) wsum[w] = inc;
    __syncthreads();
    int woff = 0;
#pragma unroll
    for (int j = 0; j < 4; ++j)
        if (j < w) woff += wsum[j];
    int ex = woff + inc - s2;
    posL[2 * t] = ex;
    posL[2 * t + 1] = ex + v0;
    __syncthreads();

    for (int i = t; i < nloc; i += 256) {
        starts[nb0 + i] = gs + posL[i];
        dinv[nb0 + i] = rsqrtf((float)degL[i] + 1.0f);
    }
    __syncthreads();

    for (int k = gs + t; k < ge; k += 256) {
        uint2 p = binned[k];
        int pos = atomicAdd(&posL[(int)p.y - nb0], 1);
        eidx[gs + pos] = (int)((p.x << 7) | (p.y & (GW - 1)));
    }
}

// ---------------- dense GEMM: T[n x 64] = bf16( (X[n x DIN] @ W[DIN x 64]) * dinv[row] ) ----------------
template <int DIN>
__global__ __launch_bounds__(256) void gemm_kernel(const float* __restrict__ X,
                                                   const float* __restrict__ W,
                                                   const float* __restrict__ dinv,
                                                   unsigned short* __restrict__ T, int n) {
    __shared__ float xs[64][33];
    __shared__ float ws[32][64];
    const int t  = threadIdx.x;
    const int n0 = blockIdx.x * 64;
    const int tc = t & 15;
    const int tr = t >> 4;

    float acc[4][4] = {};

    for (int k0 = 0; k0 < DIN; k0 += 32) {
        for (int l = t; l < 512; l += 256) {
            int r = l >> 3;
            int q = (l & 7) << 2;
            int row = n0 + r;
            float4 v = make_float4(0.f, 0.f, 0.f, 0.f);
            if (row < n) v = *reinterpret_cast<const float4*>(&X[(long)row * DIN + k0 + q]);
            xs[r][q + 0] = v.x; xs[r][q + 1] = v.y; xs[r][q + 2] = v.z; xs[r][q + 3] = v.w;
        }
        for (int l = t; l < 512; l += 256) {
            int r = l >> 4;
            int q = (l & 15) << 2;
            float4 v = *reinterpret_cast<const float4*>(&W[(long)(k0 + r) * 64 + q]);
            *reinterpret_cast<float4*>(&ws[r][q]) = v;
        }
        __syncthreads();
#pragma unroll
        for (int k = 0; k < 32; ++k) {
            float4 wv = *reinterpret_cast<const float4*>(&ws[k][tc * 4]);
#pragma unroll
            for (int j = 0; j < 4; ++j) {
                float xv = xs[tr * 4 + j][k];
                acc[j][0] += xv * wv.x;
                acc[j][1] += xv * wv.y;
                acc[j][2] += xv * wv.z;
                acc[j][3] += xv * wv.w;
            }
        }
        __syncthreads();
    }

    for (int j = 0; j < 4; ++j) {
        int row = n0 + tr * 4 + j;
        if (row < n) {
            float di = dinv[row];
            uint2 p;
            p.x = bfpack(acc[j][0] * di, acc[j][1] * di);
            p.y = bfpack(acc[j][2] * di, acc[j][3] * di);
            *reinterpret_cast<uint2*>(&T[(long)row * 64 + tc * 4]) = p;
        }
    }
}

// ---------------- gather: edge-streaming into LDS accumulators ----------------
// Block = 128 dst nodes (edges contiguous in eidx). acc[128][65] fp32 in LDS (33KB, 4 blk/CU).
// Main loop: lane = grp*8 + c; per step, 8 edges: tiny eidx load (32B span) +
// uint4 row load (8 lanes/row) + 8 ds_add_f32. No per-node dependent chain, no shuffle reduce.
// Epilogue per node: lane=channel; self-loop + bias (+ReLU+LN), write fp32.
template <int MODE>
__global__ __launch_bounds__(256) void gather2_kernel(const unsigned short* __restrict__ Tp,
                                                      const int* __restrict__ starts,
                                                      const int* __restrict__ eidx,
                                                      const float* __restrict__ dinv,
                                                      const float* __restrict__ b,
                                                      const float* __restrict__ g,
                                                      const float* __restrict__ beta,
                                                      float* __restrict__ out, int n, int E) {
    __shared__ float acc[GW * GSTRIDE];
    const char* __restrict__ Tb = (const char*)Tp;
    const int t = threadIdx.x;
    const int lane = t & 63;
    const int w = t >> 6;        // wave 0..3
    const int c = lane & 7;      // channel chunk (channels 8c..8c+7)
    const int grp = lane >> 3;   // edge group
    const int n0 = blockIdx.x * GW;
    const int nloc = min(GW, n - n0);

    for (int i = t; i < GW * GSTRIDE; i += 256) acc[i] = 0.0f;
    __syncthreads();

    int eb = starts[n0];
    int ee = (n0 + GW >= n) ? E : starts[n0 + GW];
    eb = __builtin_amdgcn_readfirstlane(eb);
    ee = __builtin_amdgcn_readfirstlane(ee);

    const unsigned cb16 = (unsigned)c * 16u;
    const unsigned c8 = (unsigned)c * 8u;

    for (int base = eb + w * 64; base < ee; base += 256) {
#pragma unroll
        for (int j = 0; j < 8; ++j) {
            int e = base + j * 8 + grp;
            if (e < ee) {
                unsigned ent = (unsigned)eidx[e];
                uint4 r = *reinterpret_cast<const uint4*>(Tb + (ent & 0xFFFFFF80u) + cb16);
                float* a = &acc[(ent & (GW - 1u)) * GSTRIDE + c8];
                atomicAdd(a + 0, bflo(r.x));
                atomicAdd(a + 1, bfhi(r.x));
                atomicAdd(a + 2, bflo(r.y));
                atomicAdd(a + 3, bfhi(r.y));
                atomicAdd(a + 4, bflo(r.z));
                atomicAdd(a + 5, bfhi(r.z));
                atomicAdd(a + 6, bflo(r.w));
                atomicAdd(a + 7, bfhi(r.w));
            }
        }
    }
    __syncthreads();

    // epilogue: one node per wave-iter, lane = channel
    const float bl = b[lane];
    float gl = 0.f, bel = 0.f;
    if (MODE == 0) { gl = g[lane]; bel = beta[lane]; }

    for (int i = w; i < nloc; i += 4) {
        const int node = n0 + i;
        float av = acc[i * GSTRIDE + lane];
        // self row: bf16 channel `lane`
        unsigned su = (unsigned)*reinterpret_cast<const unsigned short*>(Tb + (unsigned)node * 128u + (unsigned)lane * 2u);
        float self = __uint_as_float(su << 16);
        float di = dinv[node];
        float v = di * (av + self) + bl;

        if (MODE == 0) {
            v = fmaxf(v, 0.0f);
            float s = v;
#pragma unroll
            for (int off = 32; off > 0; off >>= 1) s += __shfl_xor(s, off, 64);
            float mu = s * (1.0f / 64.0f);
            float d = v - mu;
            float q = d * d;
#pragma unroll
            for (int off = 32; off > 0; off >>= 1) q += __shfl_xor(q, off, 64);
            float inv = rsqrtf(q * (1.0f / 64.0f) + LN_EPS);
            out[(long)node * 64 + lane] = d * inv * gl + bel;
        } else {
            out[(long)node * 64 + lane] = v;
        }
    }
}

extern "C" void kernel_launch(void* const* d_in, const int* in_sizes, int n_in,
                              void* d_out, int out_size, void* d_ws, size_t ws_size,
                              hipStream_t stream) {
    const float* x    = (const float*)d_in[0];
    const int*   ei   = (const int*)d_in[1];
    const float* W_in = (const float*)d_in[2];
    const float* b_in = (const float*)d_in[3];
    const float* g_in = (const float*)d_in[4];
    const float* be_in= (const float*)d_in[5];
    const float* W_h  = (const float*)d_in[6];
    const float* b_h  = (const float*)d_in[7];
    const float* g_h  = (const float*)d_in[8];
    const float* be_h = (const float*)d_in[9];
    const float* W_out= (const float*)d_in[10];
    const float* b_out= (const float*)d_in[11];
    float* out = (float*)d_out;

    const int n = in_sizes[0] / 128;   // 100000
    const int E = in_sizes[1] / 2;     // 1600000
    const int* src = ei;
    const int* dst = ei + E;

    const int bpb = (n + BUCKETS - 1) / BUCKETS;  // nodes per bucket (391)
    const int HIST_BLOCKS = 256;

    // workspace: binned[E uint2] | eidx[E i32] | partial[HB*256] | ebase[256] | gcur[256]
    //            | dinv[NP f] | starts[NP i] | T[NP*64 u16] | H[NP*64 f]
    const long NP = ((long)n + 127) & ~127L;
    uint2* binned = (uint2*)d_ws;
    int*   eidx   = (int*)(binned + E);
    int*   partial= eidx + E;
    int*   ebase  = partial + HIST_BLOCKS * BUCKETS;
    int*   gcur   = ebase + BUCKETS;
    float* dinv   = (float*)(gcur + BUCKETS);
    int*   starts = (int*)(dinv + NP);
    unsigned short* T = (unsigned short*)(starts + NP);
    float* H      = (float*)(T + NP * 64);

    // ---- CSR-transpose build via 2-level bucket sort ----
    hist_kernel<<<HIST_BLOCKS, 256, 0, stream>>>(dst, E, bpb, partial);
    scan256_kernel<<<1, 256, 0, stream>>>(partial, HIST_BLOCKS, ebase, gcur);
    bin_kernel<<<(E + CHUNK - 1) / CHUNK, 512, 0, stream>>>(src, dst, E, bpb, gcur, binned);
    build_kernel<<<BUCKETS, 256, 0, stream>>>(binned, ebase, E, bpb, n, starts, dinv, eidx);

    const int ggrid = (n + GW - 1) / GW;  // 782

    // ---- layer 1 ----
    gemm_kernel<128><<<(n + 63) / 64, 256, 0, stream>>>(x, W_in, dinv, T, n);
    gather2_kernel<0><<<ggrid, 256, 0, stream>>>(T, starts, eidx, dinv, b_in, g_in, be_in, H, n, E);

    // ---- layer 2 ----
    gemm_kernel<64><<<(n + 63) / 64, 256, 0, stream>>>(H, W_h, dinv, T, n);
    gather2_kernel<0><<<ggrid, 256, 0, stream>>>(T, starts, eidx, dinv, b_h, g_h, be_h, H, n, E);

    // ---- layer 3 (no ReLU/LN, straight to output) ----
    gemm_kernel<64><<<(n + 63) / 64, 256, 0, stream>>>(H, W_out, dinv, T, n);
    gather2_kernel<1><<<ggrid, 256, 0, stream>>>(T, starts, eidx, dinv, b_out, nullptr, nullptr, out, n, E);
}

// Round 9
// 245.646 us; speedup vs baseline: 9.0183x; 9.0183x over previous
//
#include <hip/hip_runtime.h>

// GraphEncoder: 3x (GCNConv -> [ReLU -> LayerNorm]) on N=100000 nodes, E=1.6M edges.
// Round 9: revert r8's LDS-atomic gather (712us: E*64 ds_add_f32 serialization).
// Base = round 7 (270us). Changes:
//   (a) gather: 2 nodes per wave (one per 32-lane half, 4 grp x 8 ch-lanes, quad unroll)
//       -> halves per-node prologue/epilogue overhead (half the VALU was epilogue).
//   (b) binned packed u32 (src<<9 | dst_local) -> halves bucket-sort global traffic.
// FETCH ~= 8 XCDs x T(12.8MB) is compulsory for random gather; T stays bf16.

constexpr float LN_EPS = 1e-5f;
constexpr int BUCKETS = 256;
constexpr int CHUNK = 4096;

// ---- bf16 helpers (RNE) ----
__device__ inline unsigned bf1(float x) {
    unsigned u = __float_as_uint(x);
    return (u + 0x7FFFu + ((u >> 16) & 1u)) >> 16;
}
__device__ inline unsigned bfpack(float lo, float hi) { return bf1(lo) | (bf1(hi) << 16); }
__device__ inline float bflo(unsigned r) { return __uint_as_float(r << 16); }
__device__ inline float bfhi(unsigned r) { return __uint_as_float(r & 0xFFFF0000u); }

// ---------------- hist: per-block LDS histogram of dst buckets -> partial[block][bin] ----------------
__global__ __launch_bounds__(256) void hist_kernel(const int* __restrict__ dst, int E, int bpb,
                                                   int* __restrict__ partial) {
    __shared__ int h[BUCKETS];
    const int t = threadIdx.x;
    h[t] = 0;
    __syncthreads();
    int i = blockIdx.x * blockDim.x + t;
    const int stride = gridDim.x * blockDim.x;
    for (; i < E; i += stride) atomicAdd(&h[dst[i] / bpb], 1);
    __syncthreads();
    partial[blockIdx.x * BUCKETS + t] = h[t];
}

// ---------------- scan256: column-sum partials, exclusive scan -> ebase, gcur ----------------
__global__ __launch_bounds__(256) void scan256_kernel(const int* __restrict__ partial, int nblk,
                                                      int* __restrict__ ebase, int* __restrict__ gcur) {
    __shared__ int wsum[4];
    const int t = threadIdx.x, lane = t & 63, w = t >> 6;
    int s0 = 0, s1 = 0, s2 = 0, s3 = 0;
    int i = 0;
    for (; i + 4 <= nblk; i += 4) {
        s0 += partial[(i + 0) * BUCKETS + t];
        s1 += partial[(i + 1) * BUCKETS + t];
        s2 += partial[(i + 2) * BUCKETS + t];
        s3 += partial[(i + 3) * BUCKETS + t];
    }
    for (; i < nblk; ++i) s0 += partial[i * BUCKETS + t];
    int v = s0 + s1 + s2 + s3;
    int inc = v;
#pragma unroll
    for (int off = 1; off < 64; off <<= 1) {
        int u = __shfl_up(inc, off, 64);
        if (lane >= off) inc += u;
    }
    if (lane == 63) wsum[w] = inc;
    __syncthreads();
    int woff = 0;
#pragma unroll
    for (int j = 0; j < 4; ++j)
        if (j < w) woff += wsum[j];
    int ex = woff + inc - v;
    ebase[t] = ex;
    gcur[t] = ex;
}

// ---------------- bin (pass 1): chunk -> LDS-grouped -> coalesced bursts to bucket streams ----------------
// binned entry packed: (src << 9) | (dst - bucket*bpb).  src<2^17, bpb=391<512.
__global__ __launch_bounds__(512) void bin_kernel(const int* __restrict__ src,
                                                  const int* __restrict__ dst, int E, int bpb,
                                                  int* __restrict__ gcur,
                                                  unsigned* __restrict__ binned) {
    __shared__ uint2 stag[CHUNK];
    __shared__ int cnt[BUCKETS], lstart[BUCKETS], loff[BUCKETS], gbase[BUCKETS];
    __shared__ int wsum[4];
    const int t = threadIdx.x;
    const int cb = blockIdx.x * CHUNK;
    const int csize = min(CHUNK, E - cb);

    if (t < BUCKETS) cnt[t] = 0;
    __syncthreads();

    int sr[8], dr[8];
#pragma unroll
    for (int j = 0; j < 8; ++j) {
        int i = t + j * 512;
        if (i < csize) {
            sr[j] = src[cb + i];
            dr[j] = dst[cb + i];
            atomicAdd(&cnt[dr[j] / bpb], 1);
        }
    }
    __syncthreads();

    if (t < BUCKETS) {
        const int lane = t & 63, w = t >> 6;
        int v = cnt[t];
        int inc = v;
#pragma unroll
        for (int off = 1; off < 64; off <<= 1) {
            int u = __shfl_up(inc, off, 64);
            if (lane >= off) inc += u;
        }
        if (lane == 63) wsum[w] = inc;
        __syncthreads();
        int woff = 0;
#pragma unroll
        for (int j = 0; j < 4; ++j)
            if (j < w) woff += wsum[j];
        int ex = woff + inc - v;
        lstart[t] = ex;
        loff[t] = ex;
    } else {
        __syncthreads();
    }
    __syncthreads();

#pragma unroll
    for (int j = 0; j < 8; ++j) {
        int i = t + j * 512;
        if (i < csize) {
            int b = dr[j] / bpb;
            int pos = atomicAdd(&loff[b], 1);
            stag[pos] = make_uint2((unsigned)sr[j], (unsigned)dr[j]);
        }
    }
    __syncthreads();

    if (t < BUCKETS && cnt[t] > 0) gbase[t] = atomicAdd(&gcur[t], cnt[t]);
    __syncthreads();

    for (int s = t; s < csize; s += 512) {
        uint2 p = stag[s];
        int b = (int)p.y / bpb;
        binned[gbase[b] + (s - lstart[b])] = (p.x << 9) | (p.y - (unsigned)(b * bpb));
    }
}

// ---------------- build (pass 2): per-bucket deg/dinv/starts + L2-local fine scatter ----------------
// eidx entries are BYTE OFFSETS into T (src*128) for 32-bit gather addressing.
__global__ __launch_bounds__(256) void build_kernel(const unsigned* __restrict__ binned,
                                                    const int* __restrict__ ebase, int E, int bpb, int n,
                                                    int* __restrict__ starts,
                                                    float* __restrict__ dinv,
                                                    int* __restrict__ eidx) {
    __shared__ int degL[512];
    __shared__ int posL[512];
    __shared__ int wsum[4];
    const int t = threadIdx.x, lane = t & 63, w = t >> 6;
    const int b = blockIdx.x;
    const int nb0 = b * bpb;
    const int nloc = min(bpb, n - nb0);
    if (nloc <= 0) return;
    const int gs = ebase[b];
    const int ge = (b == BUCKETS - 1) ? E : ebase[b + 1];

    degL[t] = 0;
    degL[t + 256] = 0;
    __syncthreads();

    for (int k = gs + t; k < ge; k += 256) {
        unsigned p = binned[k];
        atomicAdd(&degL[p & 511u], 1);
    }
    __syncthreads();

    int v0 = degL[2 * t], v1 = degL[2 * t + 1];
    int s2 = v0 + v1;
    int inc = s2;
#pragma unroll
    for (int off = 1; off < 64; off <<= 1) {
        int u = __shfl_up(inc, off, 64);
        if (lane >= off) inc += u;
    }
    if (lane == 63) wsum[w] = inc;
    __syncthreads();
    int woff = 0;
#pragma unroll
    for (int j = 0; j < 4; ++j)
        if (j < w) woff += wsum[j];
    int ex = woff + inc - s2;
    posL[2 * t] = ex;
    posL[2 * t + 1] = ex + v0;
    __syncthreads();

    for (int i = t; i < nloc; i += 256) {
        starts[nb0 + i] = gs + posL[i];
        dinv[nb0 + i] = rsqrtf((float)degL[i] + 1.0f);
    }
    __syncthreads();

    for (int k = gs + t; k < ge; k += 256) {
        unsigned p = binned[k];
        int pos = atomicAdd(&posL[p & 511u], 1);
        eidx[gs + pos] = (int)((p >> 9) << 7);  // byte offset: src * 128
    }
}

// ---------------- dense GEMM: T[n x 64] = bf16( (X[n x DIN] @ W[DIN x 64]) * dinv[row] ) ----------------
template <int DIN>
__global__ __launch_bounds__(256) void gemm_kernel(const float* __restrict__ X,
                                                   const float* __restrict__ W,
                                                   const float* __restrict__ dinv,
                                                   unsigned short* __restrict__ T, int n) {
    __shared__ float xs[64][33];
    __shared__ float ws[32][64];
    const int t  = threadIdx.x;
    const int n0 = blockIdx.x * 64;
    const int tc = t & 15;
    const int tr = t >> 4;

    float acc[4][4] = {};

    for (int k0 = 0; k0 < DIN; k0 += 32) {
        for (int l = t; l < 512; l += 256) {
            int r = l >> 3;
            int q = (l & 7) << 2;
            int row = n0 + r;
            float4 v = make_float4(0.f, 0.f, 0.f, 0.f);
            if (row < n) v = *reinterpret_cast<const float4*>(&X[(long)row * DIN + k0 + q]);
            xs[r][q + 0] = v.x; xs[r][q + 1] = v.y; xs[r][q + 2] = v.z; xs[r][q + 3] = v.w;
        }
        for (int l = t; l < 512; l += 256) {
            int r = l >> 4;
            int q = (l & 15) << 2;
            float4 v = *reinterpret_cast<const float4*>(&W[(long)(k0 + r) * 64 + q]);
            *reinterpret_cast<float4*>(&ws[r][q]) = v;
        }
        __syncthreads();
#pragma unroll
        for (int k = 0; k < 32; ++k) {
            float4 wv = *reinterpret_cast<const float4*>(&ws[k][tc * 4]);
#pragma unroll
            for (int j = 0; j < 4; ++j) {
                float xv = xs[tr * 4 + j][k];
                acc[j][0] += xv * wv.x;
                acc[j][1] += xv * wv.y;
                acc[j][2] += xv * wv.z;
                acc[j][3] += xv * wv.w;
            }
        }
        __syncthreads();
    }

    for (int j = 0; j < 4; ++j) {
        int row = n0 + tr * 4 + j;
        if (row < n) {
            float di = dinv[row];
            uint2 p;
            p.x = bfpack(acc[j][0] * di, acc[j][1] * di);
            p.y = bfpack(acc[j][2] * di, acc[j][3] * di);
            *reinterpret_cast<uint2*>(&T[(long)row * 64 + tc * 4]) = p;
        }
    }
}

// ---------------- fused gather + self-loop + bias (+ ReLU + LayerNorm) ----------------
// TWO nodes per wave: one per 32-lane half. Within a half: hl = grp*8 + c,
// grp in [0,4) = edge group, c in [0,8) = channel chunk (16B of the 128B bf16 row).
// Quad-unrolled edge loop: up to 4 row-loads in flight per half.
// All addresses are uniform-base + 32-bit voffset (eidx holds byte offsets).
template <int MODE>
__global__ __launch_bounds__(256) void gather_kernel(const unsigned short* __restrict__ Tp,
                                                     const int* __restrict__ starts,
                                                     const int* __restrict__ eidx,
                                                     const float* __restrict__ dinv,
                                                     const float* __restrict__ b,
                                                     const float* __restrict__ g,
                                                     const float* __restrict__ beta,
                                                     float* __restrict__ out, int n, int E) {
    const char* __restrict__ Tb = (const char*)Tp;
    const int t = threadIdx.x;
    const int lane = t & 63;
    const int hl = lane & 31;
    const int half = lane >> 5;
    const int c = hl & 7;        // channel chunk
    const int grp = hl >> 3;     // edge group 0..3
    const unsigned c16 = (unsigned)c * 16u;
    const int node = blockIdx.x * 8 + (t >> 6) * 2 + half;
    if (node >= n) return;

    int beg = starts[node];
    int end = (node == n - 1) ? E : starts[node + 1];

    float a0 = 0, a1 = 0, a2 = 0, a3 = 0, a4 = 0, a5 = 0, a6 = 0, a7 = 0;

    int k = beg + grp;
    // quad: 4 loads in flight (16 edges/node)
    for (; k + 12 < end; k += 16) {
        unsigned o0 = (unsigned)eidx[k] + c16;
        unsigned o1 = (unsigned)eidx[k + 4] + c16;
        unsigned o2 = (unsigned)eidx[k + 8] + c16;
        unsigned o3 = (unsigned)eidx[k + 12] + c16;
        uint4 r0 = *reinterpret_cast<const uint4*>(Tb + o0);
        uint4 r1 = *reinterpret_cast<const uint4*>(Tb + o1);
        uint4 r2 = *reinterpret_cast<const uint4*>(Tb + o2);
        uint4 r3 = *reinterpret_cast<const uint4*>(Tb + o3);
        a0 += bflo(r0.x); a1 += bfhi(r0.x); a2 += bflo(r0.y); a3 += bfhi(r0.y);
        a4 += bflo(r0.z); a5 += bfhi(r0.z); a6 += bflo(r0.w); a7 += bfhi(r0.w);
        a0 += bflo(r1.x); a1 += bfhi(r1.x); a2 += bflo(r1.y); a3 += bfhi(r1.y);
        a4 += bflo(r1.z); a5 += bfhi(r1.z); a6 += bflo(r1.w); a7 += bfhi(r1.w);
        a0 += bflo(r2.x); a1 += bfhi(r2.x); a2 += bflo(r2.y); a3 += bfhi(r2.y);
        a4 += bflo(r2.z); a5 += bfhi(r2.z); a6 += bflo(r2.w); a7 += bfhi(r2.w);
        a0 += bflo(r3.x); a1 += bfhi(r3.x); a2 += bflo(r3.y); a3 += bfhi(r3.y);
        a4 += bflo(r3.z); a5 += bfhi(r3.z); a6 += bflo(r3.w); a7 += bfhi(r3.w);
    }
    // pair
    for (; k + 4 < end; k += 8) {
        unsigned o0 = (unsigned)eidx[k] + c16;
        unsigned o1 = (unsigned)eidx[k + 4] + c16;
        uint4 r0 = *reinterpret_cast<const uint4*>(Tb + o0);
        uint4 r1 = *reinterpret_cast<const uint4*>(Tb + o1);
        a0 += bflo(r0.x); a1 += bfhi(r0.x); a2 += bflo(r0.y); a3 += bfhi(r0.y);
        a4 += bflo(r0.z); a5 += bfhi(r0.z); a6 += bflo(r0.w); a7 += bfhi(r0.w);
        a0 += bflo(r1.x); a1 += bfhi(r1.x); a2 += bflo(r1.y); a3 += bfhi(r1.y);
        a4 += bflo(r1.z); a5 += bfhi(r1.z); a6 += bflo(r1.w); a7 += bfhi(r1.w);
    }
    // tail (at most one more per lane)
    if (k < end) {
        unsigned o = (unsigned)eidx[k] + c16;
        uint4 r = *reinterpret_cast<const uint4*>(Tb + o);
        a0 += bflo(r.x); a1 += bfhi(r.x); a2 += bflo(r.y); a3 += bfhi(r.y);
        a4 += bflo(r.z); a5 += bfhi(r.z); a6 += bflo(r.w); a7 += bfhi(r.w);
    }

    // reduce across the 4 edge groups (hl bits 3..4; stays within the half)
#pragma unroll
    for (int off = 8; off <= 16; off <<= 1) {
        a0 += __shfl_xor(a0, off, 64); a1 += __shfl_xor(a1, off, 64);
        a2 += __shfl_xor(a2, off, 64); a3 += __shfl_xor(a3, off, 64);
        a4 += __shfl_xor(a4, off, 64); a5 += __shfl_xor(a5, off, 64);
        a6 += __shfl_xor(a6, off, 64); a7 += __shfl_xor(a7, off, 64);
    }

    // self loop + bias: out = dinv[v]*(sum + T'[v]) + b
    const float di = dinv[node];
    uint4 rs = *reinterpret_cast<const uint4*>(Tb + ((unsigned)node * 128u + c16));
    float4 bb0 = *reinterpret_cast<const float4*>(&b[c * 8]);
    float4 bb1 = *reinterpret_cast<const float4*>(&b[c * 8 + 4]);
    float v0 = di * (a0 + bflo(rs.x)) + bb0.x;
    float v1 = di * (a1 + bfhi(rs.x)) + bb0.y;
    float v2 = di * (a2 + bflo(rs.y)) + bb0.z;
    float v3 = di * (a3 + bfhi(rs.y)) + bb0.w;
    float v4 = di * (a4 + bflo(rs.z)) + bb1.x;
    float v5 = di * (a5 + bfhi(rs.z)) + bb1.y;
    float v6 = di * (a6 + bflo(rs.w)) + bb1.z;
    float v7 = di * (a7 + bfhi(rs.w)) + bb1.w;

    if (MODE == 0) {
        v0 = fmaxf(v0, 0.f); v1 = fmaxf(v1, 0.f); v2 = fmaxf(v2, 0.f); v3 = fmaxf(v3, 0.f);
        v4 = fmaxf(v4, 0.f); v5 = fmaxf(v5, 0.f); v6 = fmaxf(v6, 0.f); v7 = fmaxf(v7, 0.f);
        float s = v0 + v1 + v2 + v3 + v4 + v5 + v6 + v7;
#pragma unroll
        for (int off = 1; off <= 4; off <<= 1) s += __shfl_xor(s, off, 64);
        float mu = s * (1.0f / 64.0f);
        float d0 = v0 - mu, d1 = v1 - mu, d2 = v2 - mu, d3 = v3 - mu;
        float d4 = v4 - mu, d5 = v5 - mu, d6 = v6 - mu, d7 = v7 - mu;
        float q = d0*d0 + d1*d1 + d2*d2 + d3*d3 + d4*d4 + d5*d5 + d6*d6 + d7*d7;
#pragma unroll
        for (int off = 1; off <= 4; off <<= 1) q += __shfl_xor(q, off, 64);
        float inv = rsqrtf(q * (1.0f / 64.0f) + LN_EPS);
        float4 gg0 = *reinterpret_cast<const float4*>(&g[c * 8]);
        float4 gg1 = *reinterpret_cast<const float4*>(&g[c * 8 + 4]);
        float4 be0 = *reinterpret_cast<const float4*>(&beta[c * 8]);
        float4 be1 = *reinterpret_cast<const float4*>(&beta[c * 8 + 4]);
        if (grp == 0) {
            char* ob = (char*)out;
            float4 o0 = make_float4(d0 * inv * gg0.x + be0.x, d1 * inv * gg0.y + be0.y,
                                    d2 * inv * gg0.z + be0.z, d3 * inv * gg0.w + be0.w);
            float4 o1 = make_float4(d4 * inv * gg1.x + be1.x, d5 * inv * gg1.y + be1.y,
                                    d6 * inv * gg1.z + be1.z, d7 * inv * gg1.w + be1.w);
            unsigned oo = (unsigned)node * 256u + c16 * 2u;
            *reinterpret_cast<float4*>(ob + oo) = o0;
            *reinterpret_cast<float4*>(ob + oo + 16) = o1;
        }
    } else {
        if (grp == 0) {
            char* ob = (char*)out;
            unsigned oo = (unsigned)node * 256u + c16 * 2u;
            *reinterpret_cast<float4*>(ob + oo) = make_float4(v0, v1, v2, v3);
            *reinterpret_cast<float4*>(ob + oo + 16) = make_float4(v4, v5, v6, v7);
        }
    }
}

extern "C" void kernel_launch(void* const* d_in, const int* in_sizes, int n_in,
                              void* d_out, int out_size, void* d_ws, size_t ws_size,
                              hipStream_t stream) {
    const float* x    = (const float*)d_in[0];
    const int*   ei   = (const int*)d_in[1];
    const float* W_in = (const float*)d_in[2];
    const float* b_in = (const float*)d_in[3];
    const float* g_in = (const float*)d_in[4];
    const float* be_in= (const float*)d_in[5];
    const float* W_h  = (const float*)d_in[6];
    const float* b_h  = (const float*)d_in[7];
    const float* g_h  = (const float*)d_in[8];
    const float* be_h = (const float*)d_in[9];
    const float* W_out= (const float*)d_in[10];
    const float* b_out= (const float*)d_in[11];
    float* out = (float*)d_out;

    const int n = in_sizes[0] / 128;   // 100000
    const int E = in_sizes[1] / 2;     // 1600000
    const int* src = ei;
    const int* dst = ei + E;

    const int bpb = (n + BUCKETS - 1) / BUCKETS;  // nodes per bucket (391 < 512)
    const int HIST_BLOCKS = 256;

    // workspace: binned[E u32] | eidx[E i32] | partial[HB*256] | ebase[256] | gcur[256]
    //            | dinv[NP f] | starts[NP i] | T[NP*64 u16] | H[NP*64 f]
    const long NP = ((long)n + 127) & ~127L;
    unsigned* binned = (unsigned*)d_ws;
    int*   eidx   = (int*)(binned + E);
    int*   partial= eidx + E;
    int*   ebase  = partial + HIST_BLOCKS * BUCKETS;
    int*   gcur   = ebase + BUCKETS;
    float* dinv   = (float*)(gcur + BUCKETS);
    int*   starts = (int*)(dinv + NP);
    unsigned short* T = (unsigned short*)(starts + NP);
    float* H      = (float*)(T + NP * 64);

    // ---- CSR-transpose build via 2-level bucket sort ----
    hist_kernel<<<HIST_BLOCKS, 256, 0, stream>>>(dst, E, bpb, partial);
    scan256_kernel<<<1, 256, 0, stream>>>(partial, HIST_BLOCKS, ebase, gcur);
    bin_kernel<<<(E + CHUNK - 1) / CHUNK, 512, 0, stream>>>(src, dst, E, bpb, gcur, binned);
    build_kernel<<<BUCKETS, 256, 0, stream>>>(binned, ebase, E, bpb, n, starts, dinv, eidx);

    const int ggrid = (n + 7) / 8;  // 2 nodes/wave, 4 waves/block

    // ---- layer 1 ----
    gemm_kernel<128><<<(n + 63) / 64, 256, 0, stream>>>(x, W_in, dinv, T, n);
    gather_kernel<0><<<ggrid, 256, 0, stream>>>(T, starts, eidx, dinv, b_in, g_in, be_in, H, n, E);

    // ---- layer 2 ----
    gemm_kernel<64><<<(n + 63) / 64, 256, 0, stream>>>(H, W_h, dinv, T, n);
    gather_kernel<0><<<ggrid, 256, 0, stream>>>(T, starts, eidx, dinv, b_h, g_h, be_h, H, n, E);

    // ---- layer 3 (no ReLU/LN, straight to output) ----
    gemm_kernel<64><<<(n + 63) / 64, 256, 0, stream>>>(H, W_out, dinv, T, n);
    gather_kernel<1><<<ggrid, 256, 0, stream>>>(T, starts, eidx, dinv, b_out, nullptr, nullptr, out, n, E);
}

// Round 10
// 244.395 us; speedup vs baseline: 9.0645x; 1.0051x over previous
//
#include <hip/hip_runtime.h>

// GraphEncoder: 3x (GCNConv -> [ReLU -> LayerNorm]) on N=100000 nodes, E=1.6M edges.
// Round 10: GEMM rebuilt as register-blocked fp32 (8 nodes x 4 outs per thread,
// K-chunk 32, XOR-swizzled X tile) -> VALU-bound instead of LDS-pipe-bound.
// Old gemm: 4x4 acc, 5 LDS instr / 16 FMA = LDS-bound, 125us combined; floor ~21us.
// Gather (2 nodes/wave) and bucket-sort CSR build unchanged from round 9.

constexpr float LN_EPS = 1e-5f;
constexpr int BUCKETS = 256;
constexpr int CHUNK = 4096;

// ---- bf16 helpers (RNE) ----
__device__ inline unsigned bf1(float x) {
    unsigned u = __float_as_uint(x);
    return (u + 0x7FFFu + ((u >> 16) & 1u)) >> 16;
}
__device__ inline unsigned bfpack(float lo, float hi) { return bf1(lo) | (bf1(hi) << 16); }
__device__ inline float bflo(unsigned r) { return __uint_as_float(r << 16); }
__device__ inline float bfhi(unsigned r) { return __uint_as_float(r & 0xFFFF0000u); }

// ---------------- hist: per-block LDS histogram of dst buckets -> partial[block][bin] ----------------
__global__ __launch_bounds__(256) void hist_kernel(const int* __restrict__ dst, int E, int bpb,
                                                   int* __restrict__ partial) {
    __shared__ int h[BUCKETS];
    const int t = threadIdx.x;
    h[t] = 0;
    __syncthreads();
    int i = blockIdx.x * blockDim.x + t;
    const int stride = gridDim.x * blockDim.x;
    for (; i < E; i += stride) atomicAdd(&h[dst[i] / bpb], 1);
    __syncthreads();
    partial[blockIdx.x * BUCKETS + t] = h[t];
}

// ---------------- scan256: column-sum partials, exclusive scan -> ebase, gcur ----------------
__global__ __launch_bounds__(256) void scan256_kernel(const int* __restrict__ partial, int nblk,
                                                      int* __restrict__ ebase, int* __restrict__ gcur) {
    __shared__ int wsum[4];
    const int t = threadIdx.x, lane = t & 63, w = t >> 6;
    int s0 = 0, s1 = 0, s2 = 0, s3 = 0;
    int i = 0;
    for (; i + 4 <= nblk; i += 4) {
        s0 += partial[(i + 0) * BUCKETS + t];
        s1 += partial[(i + 1) * BUCKETS + t];
        s2 += partial[(i + 2) * BUCKETS + t];
        s3 += partial[(i + 3) * BUCKETS + t];
    }
    for (; i < nblk; ++i) s0 += partial[i * BUCKETS + t];
    int v = s0 + s1 + s2 + s3;
    int inc = v;
#pragma unroll
    for (int off = 1; off < 64; off <<= 1) {
        int u = __shfl_up(inc, off, 64);
        if (lane >= off) inc += u;
    }
    if (lane == 63) wsum[w] = inc;
    __syncthreads();
    int woff = 0;
#pragma unroll
    for (int j = 0; j < 4; ++j)
        if (j < w) woff += wsum[j];
    int ex = woff + inc - v;
    ebase[t] = ex;
    gcur[t] = ex;
}

// ---------------- bin (pass 1): chunk -> LDS-grouped -> coalesced bursts to bucket streams ----------------
// binned entry packed: (src << 9) | (dst - bucket*bpb).  src<2^17, bpb=391<512.
__global__ __launch_bounds__(512) void bin_kernel(const int* __restrict__ src,
                                                  const int* __restrict__ dst, int E, int bpb,
                                                  int* __restrict__ gcur,
                                                  unsigned* __restrict__ binned) {
    __shared__ uint2 stag[CHUNK];
    __shared__ int cnt[BUCKETS], lstart[BUCKETS], loff[BUCKETS], gbase[BUCKETS];
    __shared__ int wsum[4];
    const int t = threadIdx.x;
    const int cb = blockIdx.x * CHUNK;
    const int csize = min(CHUNK, E - cb);

    if (t < BUCKETS) cnt[t] = 0;
    __syncthreads();

    int sr[8], dr[8];
#pragma unroll
    for (int j = 0; j < 8; ++j) {
        int i = t + j * 512;
        if (i < csize) {
            sr[j] = src[cb + i];
            dr[j] = dst[cb + i];
            atomicAdd(&cnt[dr[j] / bpb], 1);
        }
    }
    __syncthreads();

    if (t < BUCKETS) {
        const int lane = t & 63, w = t >> 6;
        int v = cnt[t];
        int inc = v;
#pragma unroll
        for (int off = 1; off < 64; off <<= 1) {
            int u = __shfl_up(inc, off, 64);
            if (lane >= off) inc += u;
        }
        if (lane == 63) wsum[w] = inc;
        __syncthreads();
        int woff = 0;
#pragma unroll
        for (int j = 0; j < 4; ++j)
            if (j < w) woff += wsum[j];
        int ex = woff + inc - v;
        lstart[t] = ex;
        loff[t] = ex;
    } else {
        __syncthreads();
    }
    __syncthreads();

#pragma unroll
    for (int j = 0; j < 8; ++j) {
        int i = t + j * 512;
        if (i < csize) {
            int b = dr[j] / bpb;
            int pos = atomicAdd(&loff[b], 1);
            stag[pos] = make_uint2((unsigned)sr[j], (unsigned)dr[j]);
        }
    }
    __syncthreads();

    if (t < BUCKETS && cnt[t] > 0) gbase[t] = atomicAdd(&gcur[t], cnt[t]);
    __syncthreads();

    for (int s = t; s < csize; s += 512) {
        uint2 p = stag[s];
        int b = (int)p.y / bpb;
        binned[gbase[b] + (s - lstart[b])] = (p.x << 9) | (p.y - (unsigned)(b * bpb));
    }
}

// ---------------- build (pass 2): per-bucket deg/dinv/starts + L2-local fine scatter ----------------
// eidx entries are BYTE OFFSETS into T (src*128) for 32-bit gather addressing.
__global__ __launch_bounds__(256) void build_kernel(const unsigned* __restrict__ binned,
                                                    const int* __restrict__ ebase, int E, int bpb, int n,
                                                    int* __restrict__ starts,
                                                    float* __restrict__ dinv,
                                                    int* __restrict__ eidx) {
    __shared__ int degL[512];
    __shared__ int posL[512];
    __shared__ int wsum[4];
    const int t = threadIdx.x, lane = t & 63, w = t >> 6;
    const int b = blockIdx.x;
    const int nb0 = b * bpb;
    const int nloc = min(bpb, n - nb0);
    if (nloc <= 0) return;
    const int gs = ebase[b];
    const int ge = (b == BUCKETS - 1) ? E : ebase[b + 1];

    degL[t] = 0;
    degL[t + 256] = 0;
    __syncthreads();

    for (int k = gs + t; k < ge; k += 256) {
        unsigned p = binned[k];
        atomicAdd(&degL[p & 511u], 1);
    }
    __syncthreads();

    int v0 = degL[2 * t], v1 = degL[2 * t + 1];
    int s2 = v0 + v1;
    int inc = s2;
#pragma unroll
    for (int off = 1; off < 64; off <<= 1) {
        int u = __shfl_up(inc, off, 64);
        if (lane >= off) inc += u;
    }
    if (lane == 63) wsum[w] = inc;
    __syncthreads();
    int woff = 0;
#pragma unroll
    for (int j = 0; j < 4; ++j)
        if (j < w) woff += wsum[j];
    int ex = woff + inc - s2;
    posL[2 * t] = ex;
    posL[2 * t + 1] = ex + v0;
    __syncthreads();

    for (int i = t; i < nloc; i += 256) {
        starts[nb0 + i] = gs + posL[i];
        dinv[nb0 + i] = rsqrtf((float)degL[i] + 1.0f);
    }
    __syncthreads();

    for (int k = gs + t; k < ge; k += 256) {
        unsigned p = binned[k];
        int pos = atomicAdd(&posL[p & 511u], 1);
        eidx[gs + pos] = (int)((p >> 9) << 7);  // byte offset: src * 128
    }
}

// ---------------- dense GEMM: T[n x 64] = bf16( (X[n x DIN] @ W[DIN x 64]) * dinv[row] ) ----------------
// 256 threads; block tile 128 nodes x 64 outs; per thread 8 nodes x 4 outs (32 acc).
// K-chunk 32. X tile XOR-swizzled on node bits 3-5 so the 4 tn-groups of a wave
// (which differ only in those bits) land in distinct bank groups.
// Per 4-k: 8 xs b128 + 4 ws b128 = 144 LDS-cyc vs 256 FMA-cyc -> VALU-bound.
template <int DIN>
__global__ __launch_bounds__(256) void gemm_kernel(const float* __restrict__ X,
                                                   const float* __restrict__ W,
                                                   const float* __restrict__ dinv,
                                                   unsigned short* __restrict__ T, int n) {
    __shared__ float xs[128 * 32];   // [node][32k], slot-swizzled
    __shared__ float ws[32 * 64];    // [k][64j]
    const int t  = threadIdx.x;
    const int tj = t & 15;           // out group: j0 = tj*4
    const int tn = t >> 4;           // node group: nodes tn*8..+7
    const int nb = blockIdx.x * 128;

    float acc[8][4] = {};

    for (int k0 = 0; k0 < DIN; k0 += 32) {
        // stage X chunk: 128 nodes x 32 k = 1024 float4
#pragma unroll
        for (int m = 0; m < 4; ++m) {
            int id = t + m * 256;
            int i = id >> 3;         // node 0..127
            int q4 = id & 7;         // float4 slot in row
            int row = nb + i;
            float4 v = make_float4(0.f, 0.f, 0.f, 0.f);
            if (row < n) v = *reinterpret_cast<const float4*>(&X[(long)row * DIN + k0 + q4 * 4]);
            int sl = q4 ^ ((i >> 3) & 7);
            *reinterpret_cast<float4*>(&xs[i * 32 + sl * 4]) = v;
        }
        // stage W chunk: 32 k x 64 j = 512 float4
#pragma unroll
        for (int m = 0; m < 2; ++m) {
            int id = t + m * 256;
            int r = id >> 4;         // k 0..31
            int q4 = id & 15;
            float4 v = *reinterpret_cast<const float4*>(&W[(long)(k0 + r) * 64 + q4 * 4]);
            *reinterpret_cast<float4*>(&ws[r * 64 + q4 * 4]) = v;
        }
        __syncthreads();

#pragma unroll
        for (int k4 = 0; k4 < 8; ++k4) {
            float4 xv[8];
#pragma unroll
            for (int i = 0; i < 8; ++i) {
                int nn = tn * 8 + i;
                int sl = k4 ^ ((nn >> 3) & 7);
                xv[i] = *reinterpret_cast<const float4*>(&xs[nn * 32 + sl * 4]);
            }
#pragma unroll
            for (int kk = 0; kk < 4; ++kk) {
                float4 wv = *reinterpret_cast<const float4*>(&ws[(k4 * 4 + kk) * 64 + tj * 4]);
#pragma unroll
                for (int i = 0; i < 8; ++i) {
                    float xvv = (&xv[i].x)[kk];
                    acc[i][0] += xvv * wv.x;
                    acc[i][1] += xvv * wv.y;
                    acc[i][2] += xvv * wv.z;
                    acc[i][3] += xvv * wv.w;
                }
            }
        }
        __syncthreads();
    }

#pragma unroll
    for (int i = 0; i < 8; ++i) {
        int row = nb + tn * 8 + i;
        if (row < n) {
            float di = dinv[row];
            uint2 p;
            p.x = bfpack(acc[i][0] * di, acc[i][1] * di);
            p.y = bfpack(acc[i][2] * di, acc[i][3] * di);
            *reinterpret_cast<uint2*>(&T[(long)row * 64 + tj * 4]) = p;
        }
    }
}

// ---------------- fused gather + self-loop + bias (+ ReLU + LayerNorm) ----------------
// TWO nodes per wave: one per 32-lane half. Within a half: hl = grp*8 + c,
// grp in [0,4) = edge group, c in [0,8) = channel chunk (16B of the 128B bf16 row).
// Quad-unrolled edge loop: up to 4 row-loads in flight per half.
// All addresses are uniform-base + 32-bit voffset (eidx holds byte offsets).
template <int MODE>
__global__ __launch_bounds__(256) void gather_kernel(const unsigned short* __restrict__ Tp,
                                                     const int* __restrict__ starts,
                                                     const int* __restrict__ eidx,
                                                     const float* __restrict__ dinv,
                                                     const float* __restrict__ b,
                                                     const float* __restrict__ g,
                                                     const float* __restrict__ beta,
                                                     float* __restrict__ out, int n, int E) {
    const char* __restrict__ Tb = (const char*)Tp;
    const int t = threadIdx.x;
    const int lane = t & 63;
    const int hl = lane & 31;
    const int half = lane >> 5;
    const int c = hl & 7;        // channel chunk
    const int grp = hl >> 3;     // edge group 0..3
    const unsigned c16 = (unsigned)c * 16u;
    const int node = blockIdx.x * 8 + (t >> 6) * 2 + half;
    if (node >= n) return;

    int beg = starts[node];
    int end = (node == n - 1) ? E : starts[node + 1];

    float a0 = 0, a1 = 0, a2 = 0, a3 = 0, a4 = 0, a5 = 0, a6 = 0, a7 = 0;

    int k = beg + grp;
    // quad: 4 loads in flight (16 edges/node)
    for (; k + 12 < end; k += 16) {
        unsigned o0 = (unsigned)eidx[k] + c16;
        unsigned o1 = (unsigned)eidx[k + 4] + c16;
        unsigned o2 = (unsigned)eidx[k + 8] + c16;
        unsigned o3 = (unsigned)eidx[k + 12] + c16;
        uint4 r0 = *reinterpret_cast<const uint4*>(Tb + o0);
        uint4 r1 = *reinterpret_cast<const uint4*>(Tb + o1);
        uint4 r2 = *reinterpret_cast<const uint4*>(Tb + o2);
        uint4 r3 = *reinterpret_cast<const uint4*>(Tb + o3);
        a0 += bflo(r0.x); a1 += bfhi(r0.x); a2 += bflo(r0.y); a3 += bfhi(r0.y);
        a4 += bflo(r0.z); a5 += bfhi(r0.z); a6 += bflo(r0.w); a7 += bfhi(r0.w);
        a0 += bflo(r1.x); a1 += bfhi(r1.x); a2 += bflo(r1.y); a3 += bfhi(r1.y);
        a4 += bflo(r1.z); a5 += bfhi(r1.z); a6 += bflo(r1.w); a7 += bfhi(r1.w);
        a0 += bflo(r2.x); a1 += bfhi(r2.x); a2 += bflo(r2.y); a3 += bfhi(r2.y);
        a4 += bflo(r2.z); a5 += bfhi(r2.z); a6 += bflo(r2.w); a7 += bfhi(r2.w);
        a0 += bflo(r3.x); a1 += bfhi(r3.x); a2 += bflo(r3.y); a3 += bfhi(r3.y);
        a4 += bflo(r3.z); a5 += bfhi(r3.z); a6 += bflo(r3.w); a7 += bfhi(r3.w);
    }
    // pair
    for (; k + 4 < end; k += 8) {
        unsigned o0 = (unsigned)eidx[k] + c16;
        unsigned o1 = (unsigned)eidx[k + 4] + c16;
        uint4 r0 = *reinterpret_cast<const uint4*>(Tb + o0);
        uint4 r1 = *reinterpret_cast<const uint4*>(Tb + o1);
        a0 += bflo(r0.x); a1 += bfhi(r0.x); a2 += bflo(r0.y); a3 += bfhi(r0.y);
        a4 += bflo(r0.z); a5 += bfhi(r0.z); a6 += bflo(r0.w); a7 += bfhi(r0.w);
        a0 += bflo(r1.x); a1 += bfhi(r1.x); a2 += bflo(r1.y); a3 += bfhi(r1.y);
        a4 += bflo(r1.z); a5 += bfhi(r1.z); a6 += bflo(r1.w); a7 += bfhi(r1.w);
    }
    // tail (at most one more per lane)
    if (k < end) {
        unsigned o = (unsigned)eidx[k] + c16;
        uint4 r = *reinterpret_cast<const uint4*>(Tb + o);
        a0 += bflo(r.x); a1 += bfhi(r.x); a2 += bflo(r.y); a3 += bfhi(r.y);
        a4 += bflo(r.z); a5 += bfhi(r.z); a6 += bflo(r.w); a7 += bfhi(r.w);
    }

    // reduce across the 4 edge groups (hl bits 3..4; stays within the half)
#pragma unroll
    for (int off = 8; off <= 16; off <<= 1) {
        a0 += __shfl_xor(a0, off, 64); a1 += __shfl_xor(a1, off, 64);
        a2 += __shfl_xor(a2, off, 64); a3 += __shfl_xor(a3, off, 64);
        a4 += __shfl_xor(a4, off, 64); a5 += __shfl_xor(a5, off, 64);
        a6 += __shfl_xor(a6, off, 64); a7 += __shfl_xor(a7, off, 64);
    }

    // self loop + bias: out = dinv[v]*(sum + T'[v]) + b
    const float di = dinv[node];
    uint4 rs = *reinterpret_cast<const uint4*>(Tb + ((unsigned)node * 128u + c16));
    float4 bb0 = *reinterpret_cast<const float4*>(&b[c * 8]);
    float4 bb1 = *reinterpret_cast<const float4*>(&b[c * 8 + 4]);
    float v0 = di * (a0 + bflo(rs.x)) + bb0.x;
    float v1 = di * (a1 + bfhi(rs.x)) + bb0.y;
    float v2 = di * (a2 + bflo(rs.y)) + bb0.z;
    float v3 = di * (a3 + bfhi(rs.y)) + bb0.w;
    float v4 = di * (a4 + bflo(rs.z)) + bb1.x;
    float v5 = di * (a5 + bfhi(rs.z)) + bb1.y;
    float v6 = di * (a6 + bflo(rs.w)) + bb1.z;
    float v7 = di * (a7 + bfhi(rs.w)) + bb1.w;

    if (MODE == 0) {
        v0 = fmaxf(v0, 0.f); v1 = fmaxf(v1, 0.f); v2 = fmaxf(v2, 0.f); v3 = fmaxf(v3, 0.f);
        v4 = fmaxf(v4, 0.f); v5 = fmaxf(v5, 0.f); v6 = fmaxf(v6, 0.f); v7 = fmaxf(v7, 0.f);
        float s = v0 + v1 + v2 + v3 + v4 + v5 + v6 + v7;
#pragma unroll
        for (int off = 1; off <= 4; off <<= 1) s += __shfl_xor(s, off, 64);
        float mu = s * (1.0f / 64.0f);
        float d0 = v0 - mu, d1 = v1 - mu, d2 = v2 - mu, d3 = v3 - mu;
        float d4 = v4 - mu, d5 = v5 - mu, d6 = v6 - mu, d7 = v7 - mu;
        float q = d0*d0 + d1*d1 + d2*d2 + d3*d3 + d4*d4 + d5*d5 + d6*d6 + d7*d7;
#pragma unroll
        for (int off = 1; off <= 4; off <<= 1) q += __shfl_xor(q, off, 64);
        float inv = rsqrtf(q * (1.0f / 64.0f) + LN_EPS);
        float4 gg0 = *reinterpret_cast<const float4*>(&g[c * 8]);
        float4 gg1 = *reinterpret_cast<const float4*>(&g[c * 8 + 4]);
        float4 be0 = *reinterpret_cast<const float4*>(&beta[c * 8]);
        float4 be1 = *reinterpret_cast<const float4*>(&beta[c * 8 + 4]);
        if (grp == 0) {
            char* ob = (char*)out;
            float4 o0 = make_float4(d0 * inv * gg0.x + be0.x, d1 * inv * gg0.y + be0.y,
                                    d2 * inv * gg0.z + be0.z, d3 * inv * gg0.w + be0.w);
            float4 o1 = make_float4(d4 * inv * gg1.x + be1.x, d5 * inv * gg1.y + be1.y,
                                    d6 * inv * gg1.z + be1.z, d7 * inv * gg1.w + be1.w);
            unsigned oo = (unsigned)node * 256u + c16 * 2u;
            *reinterpret_cast<float4*>(ob + oo) = o0;
            *reinterpret_cast<float4*>(ob + oo + 16) = o1;
        }
    } else {
        if (grp == 0) {
            char* ob = (char*)out;
            unsigned oo = (unsigned)node * 256u + c16 * 2u;
            *reinterpret_cast<float4*>(ob + oo) = make_float4(v0, v1, v2, v3);
            *reinterpret_cast<float4*>(ob + oo + 16) = make_float4(v4, v5, v6, v7);
        }
    }
}

extern "C" void kernel_launch(void* const* d_in, const int* in_sizes, int n_in,
                              void* d_out, int out_size, void* d_ws, size_t ws_size,
                              hipStream_t stream) {
    const float* x    = (const float*)d_in[0];
    const int*   ei   = (const int*)d_in[1];
    const float* W_in = (const float*)d_in[2];
    const float* b_in = (const float*)d_in[3];
    const float* g_in = (const float*)d_in[4];
    const float* be_in= (const float*)d_in[5];
    const float* W_h  = (const float*)d_in[6];
    const float* b_h  = (const float*)d_in[7];
    const float* g_h  = (const float*)d_in[8];
    const float* be_h = (const float*)d_in[9];
    const float* W_out= (const float*)d_in[10];
    const float* b_out= (const float*)d_in[11];
    float* out = (float*)d_out;

    const int n = in_sizes[0] / 128;   // 100000
    const int E = in_sizes[1] / 2;     // 1600000
    const int* src = ei;
    const int* dst = ei + E;

    const int bpb = (n + BUCKETS - 1) / BUCKETS;  // nodes per bucket (391 < 512)
    const int HIST_BLOCKS = 256;

    // workspace: binned[E u32] | eidx[E i32] | partial[HB*256] | ebase[256] | gcur[256]
    //            | dinv[NP f] | starts[NP i] | T[NP*64 u16] | H[NP*64 f]
    const long NP = ((long)n + 127) & ~127L;
    unsigned* binned = (unsigned*)d_ws;
    int*   eidx   = (int*)(binned + E);
    int*   partial= eidx + E;
    int*   ebase  = partial + HIST_BLOCKS * BUCKETS;
    int*   gcur   = ebase + BUCKETS;
    float* dinv   = (float*)(gcur + BUCKETS);
    int*   starts = (int*)(dinv + NP);
    unsigned short* T = (unsigned short*)(starts + NP);
    float* H      = (float*)(T + NP * 64);

    // ---- CSR-transpose build via 2-level bucket sort ----
    hist_kernel<<<HIST_BLOCKS, 256, 0, stream>>>(dst, E, bpb, partial);
    scan256_kernel<<<1, 256, 0, stream>>>(partial, HIST_BLOCKS, ebase, gcur);
    bin_kernel<<<(E + CHUNK - 1) / CHUNK, 512, 0, stream>>>(src, dst, E, bpb, gcur, binned);
    build_kernel<<<BUCKETS, 256, 0, stream>>>(binned, ebase, E, bpb, n, starts, dinv, eidx);

    const int ggrid = (n + 7) / 8;        // gather: 2 nodes/wave, 4 waves/block
    const int mgrid = (n + 127) / 128;    // gemm: 128 nodes/block

    // ---- layer 1 ----
    gemm_kernel<128><<<mgrid, 256, 0, stream>>>(x, W_in, dinv, T, n);
    gather_kernel<0><<<ggrid, 256, 0, stream>>>(T, starts, eidx, dinv, b_in, g_in, be_in, H, n, E);

    // ---- layer 2 ----
    gemm_kernel<64><<<mgrid, 256, 0, stream>>>(H, W_h, dinv, T, n);
    gather_kernel<0><<<ggrid, 256, 0, stream>>>(T, starts, eidx, dinv, b_h, g_h, be_h, H, n, E);

    // ---- layer 3 (no ReLU/LN, straight to output) ----
    gemm_kernel<64><<<mgrid, 256, 0, stream>>>(H, W_out, dinv, T, n);
    gather_kernel<1><<<ggrid, 256, 0, stream>>>(T, starts, eidx, dinv, b_out, nullptr, nullptr, out, n, E);
}